// Round 8
// baseline (1519.651 us; speedup 1.0000x reference)
//
#include <hip/hip_runtime.h>
#include <float.h>
#include <math.h>

#define B_   16
#define NB_  8192
#define M_   1024
#define K_   16

// ===================== FROZEN ARITHMETIC (verified absmax==0, rounds 5-7) ==
// FPS d2:  dx=px-lx... d2=(dx*dx+dy*dy)+dz*dz   f32, no FMA (contract off)
//          (packed v_pk_* f32 ops are per-half IEEE-identical to scalar)
// kNN:     pn2/cn2 ascending no-FMA; dot=fma(cz,qz,fma(cy,qy,cx*qx));
//          d2=(cn2-2f*dot)+pn2
// Ties: strictly-first occurrence (lowest index) everywhere.
// ===========================================================================

typedef float v2f __attribute__((ext_vector_type(2)));

// ============================= FPS =============================
#define FPS_T 512
#define PPT   16   // points per thread = 8 pairs

__global__ __launch_bounds__(FPS_T, 2) void fps_kernel(const float* __restrict__ pos,
                                                       float* __restrict__ cent)
{
    #pragma clang fp contract(off)
    const int b = blockIdx.x;
    const int t = threadIdx.x;
    const float* pb = pos + (size_t)b * NB_ * 3;
    float* cb = cent + (size_t)b * M_ * 3;

    __shared__ float4 spts[NB_];            // 128 KB coord table (x,y,z,-)
    __shared__ float  swmax[2][FPS_T / 64]; // per-wave max, double-buffered
    __shared__ int    swidx[2];             // winning point index, double-buffered

    // coalesced, conflict-free staging (lane stride 1 over p)
    for (int p = t; p < NB_; p += FPS_T) {
        const float* s = pb + (size_t)p * 3;
        spts[p] = make_float4(s[0], s[1], s[2], 0.0f);
    }
    __syncthreads();

    // register tiles: pairs of consecutive points (t*16+2jj, t*16+2jj+1)
    v2f px2[PPT/2], py2[PPT/2], pz2[PPT/2], md2[PPT/2];
    #pragma unroll
    for (int jj = 0; jj < PPT/2; ++jj) {
        float4 a = spts[t*PPT + 2*jj];
        float4 c = spts[t*PPT + 2*jj + 1];
        px2[jj] = (v2f){a.x, c.x};
        py2[jj] = (v2f){a.y, c.y};
        pz2[jj] = (v2f){a.z, c.z};
        md2[jj] = (v2f){FLT_MAX, FLT_MAX};
    }

    float lx = pb[0], ly = pb[1], lz = pb[2];   // deterministic start at idx 0
    float c0x=0.0f,c0y=0.0f,c0z=0.0f,c1x=0.0f,c1y=0.0f,c1z=0.0f;

    for (int m = 0; m < M_; ++m) {
        // capture centroid m into thread (m>>1)'s register slot (m&1)
        if (t == (m >> 1)) {
            if (m & 1) { c1x=lx; c1y=ly; c1z=lz; }
            else       { c0x=lx; c0y=ly; c0z=lz; }
        }
        if (m == M_ - 1) break;

        // ---- packed update + packed running max (no index tracking) ----
        const v2f lxv = {lx,lx}, lyv = {ly,ly}, lzv = {lz,lz};
        v2f bmax2 = {-1.0f, -1.0f};
        #pragma unroll
        for (int jj = 0; jj < PPT/2; ++jj) {
            v2f dx = px2[jj] - lxv;
            v2f dy = py2[jj] - lyv;
            v2f dz = pz2[jj] - lzv;
            v2f d2 = (dx*dx + dy*dy) + dz*dz;       // pk mul/add, frozen rounding
            v2f mj = __builtin_elementwise_min(md2[jj], d2);
            md2[jj] = mj;
            bmax2 = __builtin_elementwise_max(bmax2, mj);
        }
        float bm = fmaxf(bmax2.x, bmax2.y);

        // ---- wave f32 max via DPP (verified chain from rounds 6/7) ----
        float v = bm;
        {
            int vi;
            vi = __builtin_amdgcn_update_dpp(__float_as_int(v), __float_as_int(v), 0xB1,  0xF, 0xF, false);
            v = fmaxf(v, __int_as_float(vi));
            vi = __builtin_amdgcn_update_dpp(__float_as_int(v), __float_as_int(v), 0x4E,  0xF, 0xF, false);
            v = fmaxf(v, __int_as_float(vi));
            vi = __builtin_amdgcn_update_dpp(__float_as_int(v), __float_as_int(v), 0x141, 0xF, 0xF, false);
            v = fmaxf(v, __int_as_float(vi));
            vi = __builtin_amdgcn_update_dpp(__float_as_int(v), __float_as_int(v), 0x140, 0xF, 0xF, false);
            v = fmaxf(v, __int_as_float(vi));
            vi = __builtin_amdgcn_update_dpp(__float_as_int(v), __float_as_int(v), 0x142, 0xF, 0xF, false);
            v = fmaxf(v, __int_as_float(vi));
            vi = __builtin_amdgcn_update_dpp(__float_as_int(v), __float_as_int(v), 0x143, 0xF, 0xF, false);
            v = fmaxf(v, __int_as_float(vi));
        }
        const float wv = __int_as_float(__builtin_amdgcn_readlane(__float_as_int(v), 63));

        const int par = m & 1;
        if ((t & 63) == 0) swmax[par][t >> 6] = wv;
        __syncthreads();                                 // barrier 1

        // global max + LOWEST wave attaining it (wave order == index order)
        const float w0 = swmax[par][0], w1 = swmax[par][1], w2 = swmax[par][2], w3 = swmax[par][3];
        const float w4 = swmax[par][4], w5 = swmax[par][5], w6 = swmax[par][6], w7 = swmax[par][7];
        const float gmax = fmaxf(fmaxf(fmaxf(w0,w1), fmaxf(w2,w3)),
                                 fmaxf(fmaxf(w4,w5), fmaxf(w6,w7)));
        int lw = 7;
        lw = (w6 == gmax) ? 6 : lw;
        lw = (w5 == gmax) ? 5 : lw;
        lw = (w4 == gmax) ? 4 : lw;
        lw = (w3 == gmax) ? 3 : lw;
        lw = (w2 == gmax) ? 2 : lw;
        lw = (w1 == gmax) ? 1 : lw;
        lw = (w0 == gmax) ? 0 : lw;

        // winner thread (lowest matching lane of lowest matching wave) finds
        // its first matching element (ascending => first occurrence) and publishes
        unsigned long long mk = __ballot(bm == gmax);
        if ((t >> 6) == lw && (t & 63) == (int)__ffsll(mk) - 1) {
            int idx = t * PPT;
            bool found = false;
            #pragma unroll
            for (int jj = 0; jj < PPT/2; ++jj) {
                if (!found && md2[jj].x == gmax) { idx = t*PPT + 2*jj;     found = true; }
                if (!found && md2[jj].y == gmax) { idx = t*PPT + 2*jj + 1; found = true; }
            }
            swidx[par] = idx;
        }
        __syncthreads();                                 // barrier 2

        const float4 c = spts[swidx[par]];               // b128 broadcast
        lx = c.x; ly = c.y; lz = c.z;
    }

    // bulk centroid writeback: thread t owns centroids 2t and 2t+1
    float* o0 = cb + (size_t)(2*t) * 3;
    o0[0]=c0x; o0[1]=c0y; o0[2]=c0z; o0[3]=c1x; o0[4]=c1y; o0[5]=c1z;
}

// ============================= kNN =============================
#define KNN_T   256
#define CHUNK   1024
#define GRP     8
#define BCAP    16
#define BSTRIDE 17

// stable sorted insert into ascending top-16 (ties keep earlier/lower index)
__device__ __forceinline__ void topk_insert(float d2, int pi, float val[16], int idx[16])
{
    int r = 0;
    #pragma unroll
    for (int j = 0; j < 16; ++j) r += (val[j] <= d2) ? 1 : 0;
    #pragma unroll
    for (int j = 15; j >= 1; --j) {
        bool sh = (j > r);
        val[j] = sh ? val[j-1] : val[j];
        idx[j] = sh ? idx[j-1] : idx[j];
    }
    #pragma unroll
    for (int j = 0; j < 16; ++j) {
        bool pl = (j == r);
        val[j] = pl ? d2 : val[j];
        idx[j] = pl ? pi : idx[j];
    }
}

// nsplit in {1,2,4,8}: WGs = B*4*nsplit; each WG scans NB_/nsplit points for
// 256 centroids. nsplit>1 -> partial lists to ws; nsplit==1 -> direct groups.
__global__ __launch_bounds__(KNN_T, 2) void knn_kernel(const float* __restrict__ pos,
    const float* __restrict__ cent, float* __restrict__ groups,
    unsigned long long* __restrict__ partials, int nsplit)
{
    #pragma clang fp contract(off)
    __shared__ float4 spts[CHUNK];                       // 16 KB: x,y,z,pn2
    __shared__ unsigned long long sbuf[KNN_T * BSTRIDE]; // ~34 KB

    const int wg = blockIdx.x;
    const int t  = threadIdx.x;
    const int per_b = 4 * nsplit;
    const int b  = wg / per_b;
    const int r  = wg % per_b;
    const int cg = r / nsplit;
    const int sp = r % nsplit;
    const int span  = NB_ / nsplit;
    const int pbase = sp * span;
    const int nchunks = span / CHUNK;

    const float* pb = pos + (size_t)b * NB_ * 3;
    const int mg = b * M_ + cg * KNN_T + t;
    const float cx = cent[(size_t)mg*3+0];
    const float cy = cent[(size_t)mg*3+1];
    const float cz = cent[(size_t)mg*3+2];
    const float cn2 = (cx*cx + cy*cy) + cz*cz;           // ascending, no fma

    float val[16]; int idx[16];
    #pragma unroll
    for (int j = 0; j < 16; ++j) { val[j] = FLT_MAX; idx[j] = 0; }
    float tau = FLT_MAX;
    int cnt = 0;
    unsigned long long* mybuf = sbuf + t * BSTRIDE;

    for (int c = 0; c < nchunks; ++c) {
        const int ps = pbase + c * CHUNK;
        __syncthreads();
        for (int p = t; p < CHUNK; p += KNN_T) {
            const float* s = pb + (size_t)(ps + p) * 3;
            float x = s[0], y = s[1], z = s[2];
            float pn2 = (x*x + y*y) + z*z;               // ascending, no fma
            spts[p] = make_float4(x, y, z, pn2);
        }
        __syncthreads();

        for (int p0 = 0; p0 < CHUNK; p0 += GRP) {
            // make room BEFORE the group (appends per group <= GRP=8)
            if (__any(cnt > BCAP - GRP)) {
                int n = cnt; cnt = 0;
                for (int i = 0; i < n; ++i) {
                    unsigned long long e = mybuf[i];
                    float d = __uint_as_float((unsigned int)(e >> 32));
                    int pi  = (int)(e & 0xFFFFFFFFu);
                    if (d < val[15]) topk_insert(d, pi, val, idx);
                }
                tau = val[15];
            }
            float4 q[GRP];
            #pragma unroll
            for (int i = 0; i < GRP; ++i) q[i] = spts[p0 + i];   // batched b128 reads
            float d2v[GRP];
            #pragma unroll
            for (int i = 0; i < GRP; ++i) {
                float dot = __builtin_fmaf(cz, q[i].z,
                            __builtin_fmaf(cy, q[i].y, cx * q[i].x)); // Eigen gemm k-rem
                d2v[i] = (cn2 - 2.0f*dot) + q[i].w;                   // no fma
            }
            #pragma unroll
            for (int i = 0; i < GRP; ++i) {
                if (d2v[i] < tau) {
                    mybuf[cnt] = ((unsigned long long)__float_as_uint(d2v[i]) << 32) |
                                 (unsigned int)(ps + p0 + i);
                    ++cnt;
                }
            }
        }
    }
    { // flush
        int n = cnt;
        for (int i = 0; i < n; ++i) {
            unsigned long long e = mybuf[i];
            float d = __uint_as_float((unsigned int)(e >> 32));
            int pi  = (int)(e & 0xFFFFFFFFu);
            if (d < val[15]) topk_insert(d, pi, val, idx);
        }
    }

    if (nsplit > 1) {
        unsigned long long* o = partials + ((size_t)mg * nsplit + sp) * 16;
        #pragma unroll
        for (int kq = 0; kq < 16; ++kq)
            o[kq] = ((unsigned long long)__float_as_uint(val[kq]) << 32) | (unsigned int)idx[kq];
    } else {
        float* g = groups + (size_t)mg * K_ * 3;
        #pragma unroll
        for (int kq = 0; kq < 16; ++kq) {
            const float* s = pb + (size_t)idx[kq] * 3;
            g[kq*3+0] = s[0]; g[kq*3+1] = s[1]; g[kq*3+2] = s[2];
        }
    }
}

__global__ __launch_bounds__(256, 2) void knn_merge(const float* __restrict__ pos,
    const unsigned long long* __restrict__ partials, float* __restrict__ groups,
    int nsplit)
{
    const int mg = blockIdx.x * 256 + threadIdx.x;   // 0..16383
    const int b  = mg >> 10;
    const float* pb = pos + (size_t)b * NB_ * 3;

    float val[16]; int idx[16];
    #pragma unroll
    for (int j = 0; j < 16; ++j) { val[j] = FLT_MAX; idx[j] = 0; }
    for (int sp = 0; sp < nsplit; ++sp) {   // ascending split -> lower idx wins ties
        const unsigned long long* l = partials + ((size_t)mg * nsplit + sp) * 16;
        #pragma unroll
        for (int kq = 0; kq < 16; ++kq) {
            unsigned long long e = l[kq];
            float d = __uint_as_float((unsigned int)(e >> 32));
            int pi  = (int)(e & 0xFFFFFFFFu);
            if (d < val[15]) topk_insert(d, pi, val, idx);
        }
    }
    float* g = groups + (size_t)mg * K_ * 3;
    #pragma unroll
    for (int kq = 0; kq < 16; ++kq) {
        const float* s = pb + (size_t)idx[kq] * 3;
        g[kq*3+0] = s[0]; g[kq*3+1] = s[1]; g[kq*3+2] = s[2];
    }
}

// ============================= host =============================
extern "C" void kernel_launch(void* const* d_in, const int* in_sizes, int n_in,
                              void* d_out, int out_size, void* d_ws, size_t ws_size,
                              hipStream_t stream)
{
    (void)in_sizes; (void)n_in; (void)out_size;
    const float* pos = (const float*)d_in[1];   // d_in[0]=x (unused), d_in[2]=batch (unused)
    float* out    = (float*)d_out;
    float* cent   = out;                         // (B*M, 3)
    float* groups = out + (size_t)B_ * M_ * 3;   // (B*M*K, 3)

    fps_kernel<<<B_, FPS_T, 0, stream>>>(pos, cent);

    const size_t lst = (size_t)B_ * M_ * 16 * sizeof(unsigned long long); // per split: 2 MB
    int nsplit = (ws_size >= 8*lst) ? 8 : (ws_size >= 4*lst) ? 4 : (ws_size >= 2*lst) ? 2 : 1;

    knn_kernel<<<B_ * 4 * nsplit, KNN_T, 0, stream>>>(pos, cent, groups,
                                                      (unsigned long long*)d_ws, nsplit);
    if (nsplit > 1)
        knn_merge<<<(B_ * M_) / 256, 256, 0, stream>>>(pos,
                                                      (const unsigned long long*)d_ws,
                                                      groups, nsplit);
}

// Round 9
// 1208.864 us; speedup vs baseline: 1.2571x; 1.2571x over previous
//
#include <hip/hip_runtime.h>
#include <float.h>
#include <math.h>

#define B_   16
#define NB_  8192
#define M_   1024
#define K_   16

// ===================== FROZEN ARITHMETIC (verified absmax==0, rounds 5-8) ==
// FPS d2:  dx=px-lx... d2=(dx*dx+dy*dy)+dz*dz   f32, no FMA (contract off)
//          (packed v_pk_* f32 ops are per-half IEEE-identical to scalar)
// kNN:     pn2/cn2 ascending no-FMA; dot=fma(cz,qz,fma(cy,qy,cx*qx));
//          d2=(cn2-2f*dot)+pn2
// Ties: strictly-first occurrence (lowest index) everywhere.
// ===========================================================================

typedef float v2f __attribute__((ext_vector_type(2)));

// ============================= FPS =============================
// 256 threads = 4 waves (1/SIMD): no intra-SIMD wave skew, narrow barrier,
// ONE barrier per iteration (double-buffered wkey kills the WAR hazard).
#define FPS_T 256
#define PPT   32
#define NPAIR (PPT/2)
#define NWAVE (FPS_T/64)

__global__ __launch_bounds__(FPS_T, 1) void fps_kernel(const float* __restrict__ pos,
                                                       float* __restrict__ cent)
{
    #pragma clang fp contract(off)
    const int b = blockIdx.x;
    const int t = threadIdx.x;
    const float* pb = pos + (size_t)b * NB_ * 3;
    float* cb = cent + (size_t)b * M_ * 3;

    __shared__ float4 spts[NB_];                        // 128 KB coord table
    __shared__ unsigned long long wkey[2][NWAVE];       // double-buffered keys

    // coalesced staging into LDS (for the per-iter broadcast read)
    for (int p = t; p < NB_; p += FPS_T) {
        const float* s = pb + (size_t)p * 3;
        spts[p] = make_float4(s[0], s[1], s[2], 0.0f);
    }

    // register fragments straight from global (L1/L2-hot; avoids the 64-way
    // LDS bank conflicts a strided spts read pattern would cause)
    v2f px2[NPAIR], py2[NPAIR], pz2[NPAIR], md2[NPAIR];
    #pragma unroll
    for (int jj = 0; jj < NPAIR; ++jj) {
        const float* s0 = pb + (size_t)(t*PPT + 2*jj) * 3;
        px2[jj] = (v2f){s0[0], s0[3]};
        py2[jj] = (v2f){s0[1], s0[4]};
        pz2[jj] = (v2f){s0[2], s0[5]};
        md2[jj] = (v2f){FLT_MAX, FLT_MAX};
    }
    __syncthreads();

    float lx = pb[0], ly = pb[1], lz = pb[2];   // deterministic start at idx 0
    // thread t owns centroids 4t..4t+3 (named regs: no dynamic indexing)
    float c0x=0,c0y=0,c0z=0,c1x=0,c1y=0,c1z=0,c2x=0,c2y=0,c2z=0,c3x=0,c3y=0,c3z=0;

    for (int m = 0; m < M_; ++m) {
        if (t == (m >> 2)) {
            const int sl = m & 3;
            if      (sl == 0) { c0x=lx; c0y=ly; c0z=lz; }
            else if (sl == 1) { c1x=lx; c1y=ly; c1z=lz; }
            else if (sl == 2) { c2x=lx; c2y=ly; c2z=lz; }
            else              { c3x=lx; c3y=ly; c3z=lz; }
        }
        if (m == M_ - 1) break;

        // ---- packed update + packed running max (frozen, r8-verified) ----
        const v2f lxv = {lx,lx}, lyv = {ly,ly}, lzv = {lz,lz};
        v2f bmax2 = {-1.0f, -1.0f};
        #pragma unroll
        for (int jj = 0; jj < NPAIR; ++jj) {
            v2f dx = px2[jj] - lxv;
            v2f dy = py2[jj] - lyv;
            v2f dz = pz2[jj] - lzv;
            v2f d2 = (dx*dx + dy*dy) + dz*dz;       // pk mul/add, frozen rounding
            v2f mj = __builtin_elementwise_min(md2[jj], d2);
            md2[jj] = mj;
            bmax2 = __builtin_elementwise_max(bmax2, mj);
        }
        float bm = fmaxf(bmax2.x, bmax2.y);

        // ---- wave f32 max via DPP (r7/r8-verified chain) ----
        float v = bm;
        {
            int vi;
            vi = __builtin_amdgcn_update_dpp(__float_as_int(v), __float_as_int(v), 0xB1,  0xF, 0xF, false);
            v = fmaxf(v, __int_as_float(vi));
            vi = __builtin_amdgcn_update_dpp(__float_as_int(v), __float_as_int(v), 0x4E,  0xF, 0xF, false);
            v = fmaxf(v, __int_as_float(vi));
            vi = __builtin_amdgcn_update_dpp(__float_as_int(v), __float_as_int(v), 0x141, 0xF, 0xF, false);
            v = fmaxf(v, __int_as_float(vi));
            vi = __builtin_amdgcn_update_dpp(__float_as_int(v), __float_as_int(v), 0x140, 0xF, 0xF, false);
            v = fmaxf(v, __int_as_float(vi));
            vi = __builtin_amdgcn_update_dpp(__float_as_int(v), __float_as_int(v), 0x142, 0xF, 0xF, false);
            v = fmaxf(v, __int_as_float(vi));
            vi = __builtin_amdgcn_update_dpp(__float_as_int(v), __float_as_int(v), 0x143, 0xF, 0xF, false);
            v = fmaxf(v, __int_as_float(vi));
        }
        const float wv = __int_as_float(__builtin_amdgcn_readlane(__float_as_int(v), 63));

        // ---- per-lane first-match scan (descending overwrite => lowest idx) ----
        int jp = -1;
        #pragma unroll
        for (int jj = NPAIR - 1; jj >= 0; --jj) {
            if (md2[jj].y == wv) jp = 2*jj + 1;
            if (md2[jj].x == wv) jp = 2*jj;
        }
        const unsigned long long mk = __ballot(jp >= 0);
        const int wl = (int)__ffsll(mk) - 1;            // lowest lane == lowest block
        const int gi = __builtin_amdgcn_readlane(t*PPT + jp, wl);

        const int par = m & 1;
        if ((t & 63) == 0)
            wkey[par][t >> 6] = ((unsigned long long)__float_as_uint(wv) << 32) |
                                (unsigned int)(~gi);    // bigger ~idx == lower idx
        __syncthreads();                                // the ONLY barrier

        unsigned long long kk = wkey[par][0];
        #pragma unroll
        for (int w = 1; w < NWAVE; ++w) {
            const unsigned long long e = wkey[par][w];
            kk = (e > kk) ? e : kk;
        }
        const int best = (int)(~(unsigned int)kk);

        const float4 c = spts[best];                    // b128 LDS broadcast
        lx = c.x; ly = c.y; lz = c.z;
    }

    // bulk centroid writeback: thread t owns centroids 4t..4t+3 (48 B, 3x b128)
    {
        float4* o = (float4*)(cb + (size_t)t * 12);
        o[0] = make_float4(c0x, c0y, c0z, c1x);
        o[1] = make_float4(c1y, c1z, c2x, c2y);
        o[2] = make_float4(c2z, c3x, c3y, c3z);
    }
}

// ============================= kNN =============================
#define KNN_T   256
#define CHUNK   1024
#define GRP     8
#define BCAP    16
#define BSTRIDE 17

// stable sorted insert into ascending top-16 (ties keep earlier/lower index)
__device__ __forceinline__ void topk_insert(float d2, int pi, float val[16], int idx[16])
{
    int r = 0;
    #pragma unroll
    for (int j = 0; j < 16; ++j) r += (val[j] <= d2) ? 1 : 0;
    #pragma unroll
    for (int j = 15; j >= 1; --j) {
        bool sh = (j > r);
        val[j] = sh ? val[j-1] : val[j];
        idx[j] = sh ? idx[j-1] : idx[j];
    }
    #pragma unroll
    for (int j = 0; j < 16; ++j) {
        bool pl = (j == r);
        val[j] = pl ? d2 : val[j];
        idx[j] = pl ? pi : idx[j];
    }
}

// nsplit in {1,2,4,8}: WGs = B*4*nsplit; each WG scans NB_/nsplit points for
// 256 centroids. nsplit>1 -> partial lists to ws; nsplit==1 -> direct groups.
__global__ __launch_bounds__(KNN_T, 2) void knn_kernel(const float* __restrict__ pos,
    const float* __restrict__ cent, float* __restrict__ groups,
    unsigned long long* __restrict__ partials, int nsplit)
{
    #pragma clang fp contract(off)
    __shared__ float4 spts[CHUNK];                       // 16 KB: x,y,z,pn2
    __shared__ unsigned long long sbuf[KNN_T * BSTRIDE]; // ~34 KB

    const int wg = blockIdx.x;
    const int t  = threadIdx.x;
    const int per_b = 4 * nsplit;
    const int b  = wg / per_b;
    const int r  = wg % per_b;
    const int cg = r / nsplit;
    const int sp = r % nsplit;
    const int span  = NB_ / nsplit;
    const int pbase = sp * span;
    const int nchunks = span / CHUNK;

    const float* pb = pos + (size_t)b * NB_ * 3;
    const int mg = b * M_ + cg * KNN_T + t;
    const float cx = cent[(size_t)mg*3+0];
    const float cy = cent[(size_t)mg*3+1];
    const float cz = cent[(size_t)mg*3+2];
    const float cn2 = (cx*cx + cy*cy) + cz*cz;           // ascending, no fma

    float val[16]; int idx[16];
    #pragma unroll
    for (int j = 0; j < 16; ++j) { val[j] = FLT_MAX; idx[j] = 0; }
    float tau = FLT_MAX;
    int cnt = 0;
    unsigned long long* mybuf = sbuf + t * BSTRIDE;

    for (int c = 0; c < nchunks; ++c) {
        const int ps = pbase + c * CHUNK;
        __syncthreads();
        for (int p = t; p < CHUNK; p += KNN_T) {
            const float* s = pb + (size_t)(ps + p) * 3;
            float x = s[0], y = s[1], z = s[2];
            float pn2 = (x*x + y*y) + z*z;               // ascending, no fma
            spts[p] = make_float4(x, y, z, pn2);
        }
        __syncthreads();

        for (int p0 = 0; p0 < CHUNK; p0 += GRP) {
            // make room BEFORE the group (appends per group <= GRP=8)
            if (__any(cnt > BCAP - GRP)) {
                int n = cnt; cnt = 0;
                for (int i = 0; i < n; ++i) {
                    unsigned long long e = mybuf[i];
                    float d = __uint_as_float((unsigned int)(e >> 32));
                    int pi  = (int)(e & 0xFFFFFFFFu);
                    if (d < val[15]) topk_insert(d, pi, val, idx);
                }
                tau = val[15];
            }
            float4 q[GRP];
            #pragma unroll
            for (int i = 0; i < GRP; ++i) q[i] = spts[p0 + i];   // batched b128 reads
            float d2v[GRP];
            #pragma unroll
            for (int i = 0; i < GRP; ++i) {
                float dot = __builtin_fmaf(cz, q[i].z,
                            __builtin_fmaf(cy, q[i].y, cx * q[i].x)); // Eigen gemm k-rem
                d2v[i] = (cn2 - 2.0f*dot) + q[i].w;                   // no fma
            }
            #pragma unroll
            for (int i = 0; i < GRP; ++i) {
                if (d2v[i] < tau) {
                    mybuf[cnt] = ((unsigned long long)__float_as_uint(d2v[i]) << 32) |
                                 (unsigned int)(ps + p0 + i);
                    ++cnt;
                }
            }
        }
    }
    { // flush
        int n = cnt;
        for (int i = 0; i < n; ++i) {
            unsigned long long e = mybuf[i];
            float d = __uint_as_float((unsigned int)(e >> 32));
            int pi  = (int)(e & 0xFFFFFFFFu);
            if (d < val[15]) topk_insert(d, pi, val, idx);
        }
    }

    if (nsplit > 1) {
        unsigned long long* o = partials + ((size_t)mg * nsplit + sp) * 16;
        #pragma unroll
        for (int kq = 0; kq < 16; ++kq)
            o[kq] = ((unsigned long long)__float_as_uint(val[kq]) << 32) | (unsigned int)idx[kq];
    } else {
        float* g = groups + (size_t)mg * K_ * 3;
        #pragma unroll
        for (int kq = 0; kq < 16; ++kq) {
            const float* s = pb + (size_t)idx[kq] * 3;
            g[kq*3+0] = s[0]; g[kq*3+1] = s[1]; g[kq*3+2] = s[2];
        }
    }
}

__global__ __launch_bounds__(256, 2) void knn_merge(const float* __restrict__ pos,
    const unsigned long long* __restrict__ partials, float* __restrict__ groups,
    int nsplit)
{
    const int mg = blockIdx.x * 256 + threadIdx.x;   // 0..16383
    const int b  = mg >> 10;
    const float* pb = pos + (size_t)b * NB_ * 3;

    float val[16]; int idx[16];
    #pragma unroll
    for (int j = 0; j < 16; ++j) { val[j] = FLT_MAX; idx[j] = 0; }
    for (int sp = 0; sp < nsplit; ++sp) {   // ascending split -> lower idx wins ties
        const unsigned long long* l = partials + ((size_t)mg * nsplit + sp) * 16;
        #pragma unroll
        for (int kq = 0; kq < 16; ++kq) {
            unsigned long long e = l[kq];
            float d = __uint_as_float((unsigned int)(e >> 32));
            int pi  = (int)(e & 0xFFFFFFFFu);
            if (d < val[15]) topk_insert(d, pi, val, idx);
        }
    }
    float* g = groups + (size_t)mg * K_ * 3;
    #pragma unroll
    for (int kq = 0; kq < 16; ++kq) {
        const float* s = pb + (size_t)idx[kq] * 3;
        g[kq*3+0] = s[0]; g[kq*3+1] = s[1]; g[kq*3+2] = s[2];
    }
}

// ============================= host =============================
extern "C" void kernel_launch(void* const* d_in, const int* in_sizes, int n_in,
                              void* d_out, int out_size, void* d_ws, size_t ws_size,
                              hipStream_t stream)
{
    (void)in_sizes; (void)n_in; (void)out_size;
    const float* pos = (const float*)d_in[1];   // d_in[0]=x (unused), d_in[2]=batch (unused)
    float* out    = (float*)d_out;
    float* cent   = out;                         // (B*M, 3)
    float* groups = out + (size_t)B_ * M_ * 3;   // (B*M*K, 3)

    fps_kernel<<<B_, FPS_T, 0, stream>>>(pos, cent);

    const size_t lst = (size_t)B_ * M_ * 16 * sizeof(unsigned long long); // per split: 2 MB
    int nsplit = (ws_size >= 8*lst) ? 8 : (ws_size >= 4*lst) ? 4 : (ws_size >= 2*lst) ? 2 : 1;

    knn_kernel<<<B_ * 4 * nsplit, KNN_T, 0, stream>>>(pos, cent, groups,
                                                      (unsigned long long*)d_ws, nsplit);
    if (nsplit > 1)
        knn_merge<<<(B_ * M_) / 256, 256, 0, stream>>>(pos,
                                                      (const unsigned long long*)d_ws,
                                                      groups, nsplit);
}